// Round 7
// baseline (533.120 us; speedup 1.0000x reference)
//
#include <hip/hip_runtime.h>
#include <hip/hip_fp16.h>
#include <stdint.h>

#define CH 128
#define OC 64
#define NG 512
#define NBLK 256      // partition blocks
#define NBMAX 4096    // max coarse buckets (nodes/256)
#define POOLB 400     // pool blocks
#define PADB 1792     // per-bucket pad reserve (7*256)

typedef unsigned int uint;
typedef unsigned short ushort;
typedef __attribute__((ext_vector_type(8))) _Float16 half8;
typedef __attribute__((ext_vector_type(4))) float floatx4;

__device__ __forceinline__ __half2 h2shfl_xor(__half2 v, int m) {
    int i = *(int*)&v;
    i = __shfl_xor(i, m);
    return *(__half2*)&i;
}

// ---------------- bucket histogram, written bucket-major ----------------
__global__ __launch_bounds__(256) void k_hist(const int* __restrict__ dst,
                                              int* __restrict__ bhT,
                                              int E, int NB, int chunk) {
    __shared__ int h[NBMAX];
    int blk = blockIdx.x, tid = threadIdx.x;
    for (int j = tid; j < NB; j += 256) h[j] = 0;
    __syncthreads();
    int lo = blk * chunk, hi = min(E, lo + chunk);
    for (int i = lo + tid; i < hi; i += 256) atomicAdd(&h[dst[i] >> 8], 1);
    __syncthreads();
    for (int j = tid; j < NB; j += 256) bhT[j * NBLK + blk] = h[j];
}

// ---------------- prefix scan (block offsets folded by consumers) ---------
__global__ __launch_bounds__(256) void k_scan1(const int* __restrict__ in,
                                               int* __restrict__ excl,
                                               int* __restrict__ bsums, int T) {
    __shared__ int sd[256];
    int tid = threadIdx.x;
    int base = blockIdx.x * 1024 + tid * 4;
    int v[4];
#pragma unroll
    for (int i = 0; i < 4; i++) v[i] = (base + i < T) ? in[base + i] : 0;
    int tsum = v[0] + v[1] + v[2] + v[3];
    int val = tsum;
    sd[tid] = val; __syncthreads();
    for (int off = 1; off < 256; off <<= 1) {
        int t = (tid >= off) ? sd[tid - off] : 0;
        __syncthreads();
        val += t; sd[tid] = val;
        __syncthreads();
    }
    int run = val - tsum;
#pragma unroll
    for (int i = 0; i < 4; i++) {
        if (base + i < T) excl[base + i] = run;
        run += v[i];
    }
    if (tid == 255) bsums[blockIdx.x] = val;
}

__global__ __launch_bounds__(128) void k_scan2(int* __restrict__ bs, int nb) {
    __shared__ int sd[128];
    int tid = threadIdx.x;
    int v = (tid < nb) ? bs[tid] : 0;
    int val = v;
    sd[tid] = val; __syncthreads();
    for (int off = 1; off < 128; off <<= 1) {
        int t = (tid >= off) ? sd[tid - off] : 0;
        __syncthreads();
        val += t; sd[tid] = val;
        __syncthreads();
    }
    if (tid < nb) bs[tid] = val - v;
}

// ------- partition: packed (src<<8)|(dst&255) into per-(bucket,block) segs ----
__global__ __launch_bounds__(256) void k_part(const int* __restrict__ src,
                                              const int* __restrict__ dst,
                                              const int* __restrict__ off,
                                              const int* __restrict__ boff,
                                              int* __restrict__ ebuf,
                                              int E, int NB, int chunk) {
    __shared__ int cur[NBMAX];
    int blk = blockIdx.x, tid = threadIdx.x;
    for (int j = tid; j < NB; j += 256) {
        int idx = j * NBLK + blk;
        cur[j] = off[idx] + boff[idx >> 10];
    }
    __syncthreads();
    int lo = blk * chunk, hi = min(E, lo + chunk);
    for (int i = lo + tid; i < hi; i += 256) {
        int s = src[i], d = dst[i];
        int pos = atomicAdd(&cur[d >> 8], 1);
        ebuf[pos] = (s << 8) | (d & 255);
    }
}

// --- CSR finalize per bucket: padded rows (x8), sentinel fill, meta pack ----
// meta[node] = (padded_row_start << 6) | (padded_deg/8); sentinel src = n.
__global__ __launch_bounds__(256) void k_csr(const int* __restrict__ ebuf,
                                             const int* __restrict__ off,
                                             const int* __restrict__ boff,
                                             int* __restrict__ meta,
                                             float* __restrict__ dinv,
                                             int* __restrict__ ssrc,
                                             int n, int NB, int E) {
    __shared__ int cnt[256], sc[256], cur[256];
    int b = blockIdx.x, tid = threadIdx.x;
    int node0 = b << 8;
    int i0 = b * NBLK;
    int bstart = off[i0] + boff[i0 >> 10];
    int bend = E;
    if (b + 1 < NB) {
        int i1 = (b + 1) * NBLK;
        bend = off[i1] + boff[i1 >> 10];
    }
    int base = bstart + b * PADB;          // padded region start
    int rend = bend + (b + 1) * PADB;      // padded region end
    for (int i = base + tid; i < rend; i += 256) ssrc[i] = n;  // sentinel init
    cnt[tid] = 0;
    __syncthreads();
    for (int i = bstart + tid; i < bend; i += 256)
        atomicAdd(&cnt[ebuf[i] & 255], 1);
    __syncthreads();
    int v = cnt[tid];
    int degp = (v + 7) & ~7;
    int val = degp;
    sc[tid] = val; __syncthreads();
    for (int o = 1; o < 256; o <<= 1) {
        int t = (tid >= o) ? sc[tid - o] : 0;
        __syncthreads();
        val += t; sc[tid] = val;
        __syncthreads();
    }
    int excl = val - degp;
    int node = node0 + tid;
    if (node < n) {
        meta[node] = ((base + excl) << 6) | (degp >> 3);
        dinv[node] = rsqrtf((float)v + 1.0f);
    }
    cur[tid] = base + excl;
    __syncthreads();
    for (int i = bstart + tid; i < bend; i += 256) {
        int e = ebuf[i];
        int pos = atomicAdd(&cur[e & 255], 1);
        ssrc[pos] = e >> 8;
    }
}

// ------ fp32 -> sliced f16 with dinv pre-scale; zero sentinel rows ---------
__global__ __launch_bounds__(256) void k_cvt(const float* __restrict__ x,
                                             const float* __restrict__ dinv,
                                             ushort* __restrict__ xb,
                                             ushort* __restrict__ yb,
                                             int n, int NS, int total) {
    int i = (blockIdx.x * 256 + threadIdx.x) * 4;
    if (i < total) {
        int node = i >> 7, c = i & 127;
        float d = dinv[node];
        float4 v = *(const float4*)(x + i);
        int sl = c >> 4, wc = c & 15;
        __half2 h0 = __floats2half2_rn(v.x * d, v.y * d);
        __half2 h1 = __floats2half2_rn(v.z * d, v.w * d);
        uint2 o;
        o.x = *(uint*)&h0; o.y = *(uint*)&h1;
        *(uint2*)(xb + (size_t)sl * NS + (size_t)node * 16 + wc) = o;
    }
    if (blockIdx.x == 0 && threadIdx.x < 128) {
        int s = threadIdx.x >> 4, ch = threadIdx.x & 15;
        xb[(size_t)s * NS + (size_t)n * 16 + ch] = 0;
        yb[(size_t)s * NS + (size_t)n * 16 + ch] = 0;
    }
}

// ------- fused prep: W1->Wt (f16 transp) ; Wc=W2*Wfc ; bc=b2*Wfc+bfc -------
__global__ __launch_bounds__(256) void k_prep(const float* __restrict__ W1,
                                              const float* __restrict__ W2,
                                              const float* __restrict__ b2,
                                              const float* __restrict__ Wfc,
                                              const float* __restrict__ bfc,
                                              ushort* __restrict__ Wt,
                                              float* __restrict__ Wc,
                                              float* __restrict__ bc) {
    int t = blockIdx.x * 256 + threadIdx.x;
    if (t < CH * CH) {
        int nc = t >> 7, k = t & 127;
        Wt[nc * CH + k] = __half_as_ushort(__float2half(W1[k * CH + nc]));
    } else if (t < CH * CH + CH * OC) {
        int u = t - CH * CH;
        int k = u >> 6, o = u & 63;
        float acc = 0.f;
        for (int j = 0; j < CH; j++) acc += W2[k * CH + j] * Wfc[j * OC + o];
        Wc[u] = acc;
    } else if (t < CH * CH + CH * OC + OC) {
        int o = t - CH * CH - CH * OC;
        float acc = bfc[o];
        for (int j = 0; j < CH; j++) acc += b2[j] * Wfc[j * OC + o];
        bc[o] = acc;
    }
}

// ---- aggregation v4: slice-pinned (blockIdx%8 -> XCD), f16 pk_add ---------
// out[s][i] = dinv_i * (sum_e Hs[s][src_e] + Hs[s][i]); Hs pre-scaled.
__global__ __launch_bounds__(256) void k_agg(const ushort* __restrict__ Hs,
                                             const int* __restrict__ meta,
                                             const int* __restrict__ ssrc,
                                             const float* __restrict__ dinv,
                                             ushort* __restrict__ out,
                                             int n, int NS) {
    int bi = blockIdx.x;
    int s = bi & 7;
    int nb = bi >> 3;
    int wid = (nb << 2) | (threadIdx.x >> 6);
    if (wid >= n) return;
    int uw = __builtin_amdgcn_readfirstlane(wid);
    int lane = threadIdx.x & 63;
    int sub = lane >> 3;          // edge slot (0..7)
    int li = lane & 7;            // channel-pair (0..7) within 16-ch slice
    const __half2* B = (const __half2*)(Hs + (size_t)s * NS);
    __half2 acc = __floats2half2_rn(0.f, 0.f);
    __half2 acc2 = acc;
    if (sub == 0) acc = B[uw * 8 + li];          // self term
    int mv = meta[uw];
    int e0 = mv >> 6;
    int iters = mv & 63;
    int it = 0;
    for (; it + 1 < iters; it += 2) {
        int e = e0 + (it << 3) + sub;
        int s0 = ssrc[e];
        int s1 = ssrc[e + 8];
        __half2 g0 = B[s0 * 8 + li];
        __half2 g1 = B[s1 * 8 + li];
        acc = __hadd2(acc, g0);
        acc2 = __hadd2(acc2, g1);
    }
    if (it < iters) {
        int e = e0 + (it << 3) + sub;
        int s0 = ssrc[e];
        acc = __hadd2(acc, B[s0 * 8 + li]);
    }
    acc = __hadd2(acc, acc2);
    acc = __hadd2(acc, h2shfl_xor(acc, 8));
    acc = __hadd2(acc, h2shfl_xor(acc, 16));
    acc = __hadd2(acc, h2shfl_xor(acc, 32));
    if (sub == 0) {
        float2 f = __half22float2(acc);
        float d = dinv[uw];
        __half2 o = __floats2half2_rn(f.x * d, f.y * d);
        ((uint*)(out + (size_t)s * NS + (size_t)uw * 16))[li] = *(uint*)&o;
    }
}

// ------ H = dinv*relu(Y*W + b) via MFMA f16; Y,H sliced f16 ------
__global__ __launch_bounds__(256) void k_gemm_mfma(const ushort* __restrict__ Y,
                                                   const ushort* __restrict__ Wt,
                                                   const float* __restrict__ bias,
                                                   const float* __restrict__ dinv,
                                                   ushort* __restrict__ H,
                                                   int n, int NS) {
    __shared__ __align__(16) ushort As[128][136];
    int tid = threadIdx.x;
    int r0 = blockIdx.x * 128;
#pragma unroll
    for (int i = 0; i < 8; i++) {
        int idx = tid + i * 256;
        int row = idx >> 4;
        int c8 = (idx & 15) * 8;
        int r = r0 + row;
        uint4 v = make_uint4(0u, 0u, 0u, 0u);
        if (r < n) {
            int sl = c8 >> 4, wc = c8 & 15;
            v = *(const uint4*)(Y + (size_t)sl * NS + (size_t)r * 16 + wc);
        }
        *(uint4*)&As[row][c8] = v;
    }
    __syncthreads();
    int w = tid >> 6, lane = tid & 63;
    int qm = lane & 15, quad = lane >> 4;
    floatx4 acc[2][8];
#pragma unroll
    for (int mi = 0; mi < 2; mi++)
#pragma unroll
        for (int nt = 0; nt < 8; nt++) acc[mi][nt] = (floatx4){0.f, 0.f, 0.f, 0.f};
#pragma unroll
    for (int ks = 0; ks < 4; ks++) {
        int k0 = ks * 32 + quad * 8;
        half8 va0 = *(const half8*)&As[w * 32 + qm][k0];
        half8 va1 = *(const half8*)&As[w * 32 + 16 + qm][k0];
#pragma unroll
        for (int nt = 0; nt < 8; nt++) {
            half8 b = *(const half8*)(Wt + (nt * 16 + qm) * CH + k0);
            acc[0][nt] = __builtin_amdgcn_mfma_f32_16x16x32_f16(va0, b, acc[0][nt], 0, 0, 0);
            acc[1][nt] = __builtin_amdgcn_mfma_f32_16x16x32_f16(va1, b, acc[1][nt], 0, 0, 0);
        }
    }
#pragma unroll
    for (int mi = 0; mi < 2; mi++) {
#pragma unroll
        for (int reg = 0; reg < 4; reg++) {
            int r = r0 + w * 32 + mi * 16 + quad * 4 + reg;
            if (r >= n) continue;
            float d = dinv[r];
#pragma unroll
            for (int nt = 0; nt < 8; nt++) {
                int cidx = nt * 16 + qm;
                float val = fmaxf(acc[mi][nt][reg] + bias[cidx], 0.f) * d;
                H[(size_t)(cidx >> 4) * NS + (size_t)r * 16 + (cidx & 15)] =
                    __half_as_ushort(__float2half(val));
            }
        }
    }
}

// -------- pool: node-range sweep over sliced f16, fp32 atomics flush --------
__global__ __launch_bounds__(256) void k_pool(const ushort* __restrict__ Z,
                                              const int* __restrict__ batch,
                                              float* __restrict__ Qs,
                                              float* __restrict__ cnt,
                                              int n, int NS, int npb) {
    int lo = blockIdx.x * npb;
    if (lo >= n) return;
    int hi = min(n, lo + npb);
    int w = threadIdx.x >> 6, lane = threadIdx.x & 63;
    int c = lane * 2;
    int sl = c >> 4, wc = c & 15;
    const ushort* Zs = Z + (size_t)sl * NS + wc;
    float a0 = 0.f, a1 = 0.f;
    int curg = -1, rc = 0;
    for (int i = lo + w; i < hi; i += 4) {
        int g = batch[i];
        if (g != curg) {
            if (rc > 0) {
                atomicAdd(&Qs[curg * CH + c], a0);
                atomicAdd(&Qs[curg * CH + c + 1], a1);
                if (lane == 0) atomicAdd(&cnt[curg], (float)rc);
            }
            curg = g; a0 = a1 = 0.f; rc = 0;
        }
        uint v = *(const uint*)(Zs + (size_t)i * 16);
        float2 f = __half22float2(*(__half2*)&v);
        a0 += f.x; a1 += f.y; rc++;
    }
    if (rc > 0) {
        atomicAdd(&Qs[curg * CH + c], a0);
        atomicAdd(&Qs[curg * CH + c + 1], a1);
        if (lane == 0) atomicAdd(&cnt[curg], (float)rc);
    }
}

// ---------------- out = (Qs/cnt)*Wc + bc ----------------
__global__ __launch_bounds__(256) void k_out(const float* __restrict__ Qs,
                                             const float* __restrict__ cnt,
                                             const float* __restrict__ Wc,
                                             const float* __restrict__ bc,
                                             float* __restrict__ out) {
    int t = blockIdx.x * 256 + threadIdx.x;
    int g = t >> 6, o = t & 63;
    float invc = 1.f / fmaxf(cnt[g], 1.f);
    float acc = 0.f;
    for (int k = 0; k < CH; k++) acc += Qs[g * CH + k] * Wc[k * OC + o];
    out[t] = acc * invc + bc[o];
}

extern "C" void kernel_launch(void* const* d_in, const int* in_sizes, int n_in,
                              void* d_out, int out_size, void* d_ws, size_t ws_size,
                              hipStream_t stream) {
    const float* x   = (const float*)d_in[0];
    const float* W1  = (const float*)d_in[1];
    const float* b1  = (const float*)d_in[2];
    const float* W2  = (const float*)d_in[3];
    const float* b2  = (const float*)d_in[4];
    const float* Wfc = (const float*)d_in[5];
    const float* bfc = (const float*)d_in[6];
    const int* edges = (const int*)d_in[7];
    const int* batch = (const int*)d_in[8];

    const int n = in_sizes[8];        // 100000
    const int E = in_sizes[7] / 2;    // 1600000
    const int* esrc = edges;
    const int* edst = edges + E;

    const int NB = (n + 255) >> 8;            // 391 coarse buckets
    const int T = NB * NBLK;
    const int chunk = (E + NBLK - 1) / NBLK;
    const int NS = (n + 1) * 16;              // per-slice stride (ushorts), +sentinel

    char* p = (char*)d_ws;
    auto carve = [&](size_t bytes) {
        void* r = (void*)p;
        p += (bytes + 255) & ~(size_t)255;
        return r;
    };
    int*    bhT       = (int*)carve((size_t)T * 4);
    int*    off       = (int*)carve((size_t)T * 4);
    int*    bsums     = (int*)carve(512);
    int*    ebuf      = (int*)carve((size_t)E * 4);
    int*    meta      = (int*)carve((size_t)n * 4);
    float*  dinv      = (float*)carve((size_t)n * 4);
    int*    ssrc      = (int*)carve(((size_t)E + (size_t)NB * PADB) * 4);
    ushort* xb        = (ushort*)carve((size_t)8 * NS * 2);   // x-sliced, later h1
    ushort* yb        = (ushort*)carve((size_t)8 * NS * 2);   // y, later z
    ushort* Wt        = (ushort*)carve((size_t)CH * CH * 2);
    float*  q         = (float*)carve((size_t)NG * CH * 4);
    float*  cnt       = (float*)carve((size_t)NG * 4);
    float*  Wc        = (float*)carve((size_t)CH * OC * 4);
    float*  bc        = (float*)carve((size_t)OC * 4);

    int nScanBlocks = (T + 1023) / 1024;
    int npb = (n + POOLB - 1) / POOLB;
    int aggBlocks = ((n + 3) / 4) * 8;

    hipMemsetAsync(q, 0, (size_t)(NG * CH + NG) * 4, stream);

    // CSR build (atomic-free global ordering, padded rows)
    k_hist<<<NBLK, 256, 0, stream>>>(edst, bhT, E, NB, chunk);
    k_scan1<<<nScanBlocks, 256, 0, stream>>>(bhT, off, bsums, T);
    k_scan2<<<1, 128, 0, stream>>>(bsums, nScanBlocks);
    k_part<<<NBLK, 256, 0, stream>>>(esrc, edst, off, bsums, ebuf, E, NB, chunk);
    k_csr<<<NB, 256, 0, stream>>>(ebuf, off, bsums, meta, dinv, ssrc, n, NB, E);

    // features + weight prep
    k_cvt<<<(n * CH / 4 + 255) / 256, 256, 0, stream>>>(x, dinv, xb, yb, n, NS, n * CH);
    k_prep<<<(CH * CH + CH * OC + OC + 255) / 256, 256, 0, stream>>>(
        W1, W2, b2, Wfc, bfc, Wt, Wc, bc);
    // y = dinv*(sum Xs + self)   (xb -> yb)
    k_agg<<<aggBlocks, 256, 0, stream>>>(xb, meta, ssrc, dinv, yb, n, NS);
    // h1s = dinv*relu(y*W1 + b1)   (yb -> xb)
    k_gemm_mfma<<<(n + 127) / 128, 256, 0, stream>>>(yb, Wt, b1, dinv, xb, n, NS);
    // z = dinv*(sum H1s + self)   (xb -> yb)
    k_agg<<<aggBlocks, 256, 0, stream>>>(xb, meta, ssrc, dinv, yb, n, NS);
    // q = sum-pool(z), cnt via atomics
    k_pool<<<POOLB, 256, 0, stream>>>(yb, batch, q, cnt, n, NS, npb);
    // out = (q/cnt)*Wc + bc
    k_out<<<(NG * OC + 255) / 256, 256, 0, stream>>>(q, cnt, Wc, bc, (float*)d_out);
}

// Round 8
// 334.149 us; speedup vs baseline: 1.5955x; 1.5955x over previous
//
#include <hip/hip_runtime.h>
#include <hip/hip_fp16.h>
#include <stdint.h>

#define CH 128
#define OC 64
#define NG 512
#define NBLK 256      // partition blocks
#define NBMAX 4096    // max coarse buckets (nodes/256)
#define POOLB 400     // pool blocks
#define PADB 3840     // per-bucket pad reserve (15*256)

typedef unsigned int uint;
typedef unsigned short ushort;
typedef __attribute__((ext_vector_type(8))) _Float16 half8;
typedef __attribute__((ext_vector_type(4))) float floatx4;

__device__ __forceinline__ __half2 h2(uint u) { return *(__half2*)&u; }

// ---------------- bucket histogram, written bucket-major ----------------
__global__ __launch_bounds__(256) void k_hist(const int* __restrict__ dst,
                                              int* __restrict__ bhT,
                                              int E, int NB, int chunk) {
    __shared__ int h[NBMAX];
    int blk = blockIdx.x, tid = threadIdx.x;
    for (int j = tid; j < NB; j += 256) h[j] = 0;
    __syncthreads();
    int lo = blk * chunk, hi = min(E, lo + chunk);
    for (int i = lo + tid; i < hi; i += 256) atomicAdd(&h[dst[i] >> 8], 1);
    __syncthreads();
    for (int j = tid; j < NB; j += 256) bhT[j * NBLK + blk] = h[j];
}

// ---------------- prefix scan (block offsets folded by consumers) ---------
__global__ __launch_bounds__(256) void k_scan1(const int* __restrict__ in,
                                               int* __restrict__ excl,
                                               int* __restrict__ bsums, int T) {
    __shared__ int sd[256];
    int tid = threadIdx.x;
    int base = blockIdx.x * 1024 + tid * 4;
    int v[4];
#pragma unroll
    for (int i = 0; i < 4; i++) v[i] = (base + i < T) ? in[base + i] : 0;
    int tsum = v[0] + v[1] + v[2] + v[3];
    int val = tsum;
    sd[tid] = val; __syncthreads();
    for (int off = 1; off < 256; off <<= 1) {
        int t = (tid >= off) ? sd[tid - off] : 0;
        __syncthreads();
        val += t; sd[tid] = val;
        __syncthreads();
    }
    int run = val - tsum;
#pragma unroll
    for (int i = 0; i < 4; i++) {
        if (base + i < T) excl[base + i] = run;
        run += v[i];
    }
    if (tid == 255) bsums[blockIdx.x] = val;
}

__global__ __launch_bounds__(128) void k_scan2(int* __restrict__ bs, int nb) {
    __shared__ int sd[128];
    int tid = threadIdx.x;
    int v = (tid < nb) ? bs[tid] : 0;
    int val = v;
    sd[tid] = val; __syncthreads();
    for (int off = 1; off < 128; off <<= 1) {
        int t = (tid >= off) ? sd[tid - off] : 0;
        __syncthreads();
        val += t; sd[tid] = val;
        __syncthreads();
    }
    if (tid < nb) bs[tid] = val - v;
}

// ------- partition: packed (src<<8)|(dst&255) into per-(bucket,block) segs ----
__global__ __launch_bounds__(256) void k_part(const int* __restrict__ src,
                                              const int* __restrict__ dst,
                                              const int* __restrict__ off,
                                              const int* __restrict__ boff,
                                              int* __restrict__ ebuf,
                                              int E, int NB, int chunk) {
    __shared__ int cur[NBMAX];
    int blk = blockIdx.x, tid = threadIdx.x;
    for (int j = tid; j < NB; j += 256) {
        int idx = j * NBLK + blk;
        cur[j] = off[idx] + boff[idx >> 10];
    }
    __syncthreads();
    int lo = blk * chunk, hi = min(E, lo + chunk);
    for (int i = lo + tid; i < hi; i += 256) {
        int s = src[i], d = dst[i];
        int pos = atomicAdd(&cur[d >> 8], 1);
        ebuf[pos] = (s << 8) | (d & 255);
    }
}

// --- CSR finalize per bucket: rows padded x16, sentinel fill, meta pack ----
// meta[node] = (padded_row_start << 7) | (padded_deg/16); sentinel src = n.
__global__ __launch_bounds__(256) void k_csr(const int* __restrict__ ebuf,
                                             const int* __restrict__ off,
                                             const int* __restrict__ boff,
                                             int* __restrict__ meta,
                                             float* __restrict__ dinv,
                                             int* __restrict__ ssrc,
                                             int n, int NB, int E) {
    __shared__ int cnt[256], sc[256], cur[256];
    int b = blockIdx.x, tid = threadIdx.x;
    int node0 = b << 8;
    int i0 = b * NBLK;
    int bstart = off[i0] + boff[i0 >> 10];
    int bend = E;
    if (b + 1 < NB) {
        int i1 = (b + 1) * NBLK;
        bend = off[i1] + boff[i1 >> 10];
    }
    int base = bstart + b * PADB;          // padded region start
    int rend = bend + (b + 1) * PADB;      // padded region end
    for (int i = base + tid; i < rend; i += 256) ssrc[i] = n;  // sentinel init
    cnt[tid] = 0;
    __syncthreads();
    for (int i = bstart + tid; i < bend; i += 256)
        atomicAdd(&cnt[ebuf[i] & 255], 1);
    __syncthreads();
    int v = cnt[tid];
    int degp = (v + 15) & ~15;
    int val = degp;
    sc[tid] = val; __syncthreads();
    for (int o = 1; o < 256; o <<= 1) {
        int t = (tid >= o) ? sc[tid - o] : 0;
        __syncthreads();
        val += t; sc[tid] = val;
        __syncthreads();
    }
    int excl = val - degp;
    int node = node0 + tid;
    if (node < n) {
        meta[node] = ((base + excl) << 7) | (degp >> 4);
        dinv[node] = rsqrtf((float)v + 1.0f);
    }
    cur[tid] = base + excl;
    __syncthreads();
    for (int i = bstart + tid; i < bend; i += 256) {
        int e = ebuf[i];
        int pos = atomicAdd(&cur[e & 255], 1);
        ssrc[pos] = e >> 8;
    }
}

// ------ fp32 -> f16 row-major with dinv pre-scale; zero sentinel row -------
__global__ __launch_bounds__(256) void k_cvt(const float* __restrict__ x,
                                             const float* __restrict__ dinv,
                                             ushort* __restrict__ xb,
                                             int n, int total) {
    int i = (blockIdx.x * 256 + threadIdx.x) * 4;
    if (i < total) {
        float d = dinv[i >> 7];
        float4 v = *(const float4*)(x + i);
        __half2 h0 = __floats2half2_rn(v.x * d, v.y * d);
        __half2 h1 = __floats2half2_rn(v.z * d, v.w * d);
        uint2 o;
        o.x = *(uint*)&h0; o.y = *(uint*)&h1;
        *(uint2*)(xb + i) = o;
    }
    if (blockIdx.x == 0 && threadIdx.x < CH)
        xb[(size_t)n * CH + threadIdx.x] = 0;   // sentinel row
}

// -- fused prep: W1->Wt f16 transp ; Wc=W2*Wfc ; bc=b2*Wfc+bfc ; zero q/cnt --
__global__ __launch_bounds__(256) void k_prep(const float* __restrict__ W1,
                                              const float* __restrict__ W2,
                                              const float* __restrict__ b2,
                                              const float* __restrict__ Wfc,
                                              const float* __restrict__ bfc,
                                              ushort* __restrict__ Wt,
                                              float* __restrict__ Wc,
                                              float* __restrict__ bc,
                                              float* __restrict__ q,
                                              float* __restrict__ cnt) {
    int t = blockIdx.x * 256 + threadIdx.x;
    int stride = gridDim.x * 256;
    for (int z = t; z < NG * CH; z += stride) q[z] = 0.f;
    for (int z = t; z < NG; z += stride) cnt[z] = 0.f;
    if (t < CH * CH) {
        int nc = t >> 7, k = t & 127;
        Wt[nc * CH + k] = __half_as_ushort(__float2half(W1[k * CH + nc]));
    } else if (t < CH * CH + CH * OC) {
        int u = t - CH * CH;
        int k = u >> 6, o = u & 63;
        float acc = 0.f;
        for (int j = 0; j < CH; j++) acc += W2[k * CH + j] * Wfc[j * OC + o];
        Wc[u] = acc;
    } else if (t < CH * CH + CH * OC + OC) {
        int o = t - CH * CH - CH * OC;
        float acc = bfc[o];
        for (int j = 0; j < CH; j++) acc += b2[j] * Wfc[j * OC + o];
        bc[o] = acc;
    }
}

// ---- aggregation v5: quarter-wave, pad-16 CSR, f16 pk_add, fp32 reduce ----
// out = dinv_dst * (sum_e Hs[src_e] + Hs[dst]); Hs pre-scaled by dinv.
__global__ __launch_bounds__(256) void k_agg(const ushort* __restrict__ Hs,
                                             const int* __restrict__ meta,
                                             const int* __restrict__ ssrc,
                                             const float* __restrict__ dinv,
                                             ushort* __restrict__ out, int n) {
    int wid = (blockIdx.x << 2) | (threadIdx.x >> 6);
    if (wid >= n) return;
    int uw = __builtin_amdgcn_readfirstlane(wid);
    int lane = threadIdx.x & 63;
    int sub = lane >> 4;          // edge slot 0..3
    int li = lane & 15;           // 16 lanes x 8ch = 128 ch
    int c = li * 8;
    __half2 A0, A1, A2, A3;
    A0 = A1 = A2 = A3 = __floats2half2_rn(0.f, 0.f);
    if (sub == 0) {               // self term
        uint4 sv = *(const uint4*)(Hs + ((size_t)uw << 7) + c);
        A0 = h2(sv.x); A1 = h2(sv.y); A2 = h2(sv.z); A3 = h2(sv.w);
    }
    int mv = meta[uw];
    int e0 = mv >> 7;
    int iters = mv & 127;
    for (int it = 0; it < iters; ++it) {
        int e = e0 + (it << 4) + sub;
        int s0 = ssrc[e];
        int s1 = ssrc[e + 4];
        int s2 = ssrc[e + 8];
        int s3 = ssrc[e + 12];
        uint4 g0 = *(const uint4*)(Hs + (s0 << 7) + c);
        uint4 g1 = *(const uint4*)(Hs + (s1 << 7) + c);
        uint4 g2 = *(const uint4*)(Hs + (s2 << 7) + c);
        uint4 g3 = *(const uint4*)(Hs + (s3 << 7) + c);
        A0 = __hadd2(A0, __hadd2(__hadd2(h2(g0.x), h2(g1.x)), __hadd2(h2(g2.x), h2(g3.x))));
        A1 = __hadd2(A1, __hadd2(__hadd2(h2(g0.y), h2(g1.y)), __hadd2(h2(g2.y), h2(g3.y))));
        A2 = __hadd2(A2, __hadd2(__hadd2(h2(g0.z), h2(g1.z)), __hadd2(h2(g2.z), h2(g3.z))));
        A3 = __hadd2(A3, __hadd2(__hadd2(h2(g0.w), h2(g1.w)), __hadd2(h2(g2.w), h2(g3.w))));
    }
    float2 f0 = __half22float2(A0);
    float2 f1 = __half22float2(A1);
    float2 f2 = __half22float2(A2);
    float2 f3 = __half22float2(A3);
    float v0 = f0.x, v1 = f0.y, v2 = f1.x, v3 = f1.y;
    float v4 = f2.x, v5 = f2.y, v6 = f3.x, v7 = f3.y;
    v0 += __shfl_xor(v0, 16); v0 += __shfl_xor(v0, 32);
    v1 += __shfl_xor(v1, 16); v1 += __shfl_xor(v1, 32);
    v2 += __shfl_xor(v2, 16); v2 += __shfl_xor(v2, 32);
    v3 += __shfl_xor(v3, 16); v3 += __shfl_xor(v3, 32);
    v4 += __shfl_xor(v4, 16); v4 += __shfl_xor(v4, 32);
    v5 += __shfl_xor(v5, 16); v5 += __shfl_xor(v5, 32);
    v6 += __shfl_xor(v6, 16); v6 += __shfl_xor(v6, 32);
    v7 += __shfl_xor(v7, 16); v7 += __shfl_xor(v7, 32);
    if (sub == 0) {
        float d = dinv[uw];
        __half2 o0 = __floats2half2_rn(v0 * d, v1 * d);
        __half2 o1 = __floats2half2_rn(v2 * d, v3 * d);
        __half2 o2 = __floats2half2_rn(v4 * d, v5 * d);
        __half2 o3 = __floats2half2_rn(v6 * d, v7 * d);
        uint4 o;
        o.x = *(uint*)&o0; o.y = *(uint*)&o1;
        o.z = *(uint*)&o2; o.w = *(uint*)&o3;
        *(uint4*)(out + ((size_t)uw << 7) + c) = o;
    }
}

// ------ H = dinv*relu(Y*W + b) via MFMA f16; row-major f16 ------
__global__ __launch_bounds__(256) void k_gemm_mfma(const ushort* __restrict__ Y,
                                                   const ushort* __restrict__ Wt,
                                                   const float* __restrict__ bias,
                                                   const float* __restrict__ dinv,
                                                   ushort* __restrict__ H, int n) {
    __shared__ __align__(16) ushort As[128][136];
    int tid = threadIdx.x;
    int r0 = blockIdx.x * 128;
#pragma unroll
    for (int i = 0; i < 8; i++) {
        int idx = tid + i * 256;
        int row = idx >> 4;
        int c8 = (idx & 15) * 8;
        int r = r0 + row;
        uint4 v = make_uint4(0u, 0u, 0u, 0u);
        if (r < n) v = *(const uint4*)(Y + (size_t)r * CH + c8);
        *(uint4*)&As[row][c8] = v;
    }
    __syncthreads();
    int w = tid >> 6, lane = tid & 63;
    int qm = lane & 15, quad = lane >> 4;
    floatx4 acc[2][8];
#pragma unroll
    for (int mi = 0; mi < 2; mi++)
#pragma unroll
        for (int nt = 0; nt < 8; nt++) acc[mi][nt] = (floatx4){0.f, 0.f, 0.f, 0.f};
#pragma unroll
    for (int ks = 0; ks < 4; ks++) {
        int k0 = ks * 32 + quad * 8;
        half8 va0 = *(const half8*)&As[w * 32 + qm][k0];
        half8 va1 = *(const half8*)&As[w * 32 + 16 + qm][k0];
#pragma unroll
        for (int nt = 0; nt < 8; nt++) {
            half8 b = *(const half8*)(Wt + (nt * 16 + qm) * CH + k0);
            acc[0][nt] = __builtin_amdgcn_mfma_f32_16x16x32_f16(va0, b, acc[0][nt], 0, 0, 0);
            acc[1][nt] = __builtin_amdgcn_mfma_f32_16x16x32_f16(va1, b, acc[1][nt], 0, 0, 0);
        }
    }
#pragma unroll
    for (int mi = 0; mi < 2; mi++) {
#pragma unroll
        for (int reg = 0; reg < 4; reg++) {
            int r = r0 + w * 32 + mi * 16 + quad * 4 + reg;
            if (r >= n) continue;
            float d = dinv[r];
#pragma unroll
            for (int nt = 0; nt < 8; nt++) {
                int cidx = nt * 16 + qm;
                float val = fmaxf(acc[mi][nt][reg] + bias[cidx], 0.f) * d;
                H[(size_t)r * CH + cidx] = __half_as_ushort(__float2half(val));
            }
        }
    }
}

// -------- pool: node-range sweep over f16 rows, fp32 atomics flush ---------
__global__ __launch_bounds__(256) void k_pool(const ushort* __restrict__ Z,
                                              const int* __restrict__ batch,
                                              float* __restrict__ Qs,
                                              float* __restrict__ cnt,
                                              int n, int npb) {
    int lo = blockIdx.x * npb;
    if (lo >= n) return;
    int hi = min(n, lo + npb);
    int w = threadIdx.x >> 6, lane = threadIdx.x & 63;
    int c = lane * 2;
    float a0 = 0.f, a1 = 0.f;
    int curg = -1, rc = 0;
    for (int i = lo + w; i < hi; i += 4) {
        int g = batch[i];
        if (g != curg) {
            if (rc > 0) {
                atomicAdd(&Qs[curg * CH + c], a0);
                atomicAdd(&Qs[curg * CH + c + 1], a1);
                if (lane == 0) atomicAdd(&cnt[curg], (float)rc);
            }
            curg = g; a0 = a1 = 0.f; rc = 0;
        }
        uint v = *(const uint*)(Z + (size_t)i * CH + c);
        float2 f = __half22float2(h2(v));
        a0 += f.x; a1 += f.y; rc++;
    }
    if (rc > 0) {
        atomicAdd(&Qs[curg * CH + c], a0);
        atomicAdd(&Qs[curg * CH + c + 1], a1);
        if (lane == 0) atomicAdd(&cnt[curg], (float)rc);
    }
}

// ---------------- out = (Qs/cnt)*Wc + bc ----------------
__global__ __launch_bounds__(256) void k_out(const float* __restrict__ Qs,
                                             const float* __restrict__ cnt,
                                             const float* __restrict__ Wc,
                                             const float* __restrict__ bc,
                                             float* __restrict__ out) {
    int t = blockIdx.x * 256 + threadIdx.x;
    int g = t >> 6, o = t & 63;
    float invc = 1.f / fmaxf(cnt[g], 1.f);
    float acc = 0.f;
    for (int k = 0; k < CH; k++) acc += Qs[g * CH + k] * Wc[k * OC + o];
    out[t] = acc * invc + bc[o];
}

extern "C" void kernel_launch(void* const* d_in, const int* in_sizes, int n_in,
                              void* d_out, int out_size, void* d_ws, size_t ws_size,
                              hipStream_t stream) {
    const float* x   = (const float*)d_in[0];
    const float* W1  = (const float*)d_in[1];
    const float* b1  = (const float*)d_in[2];
    const float* W2  = (const float*)d_in[3];
    const float* b2  = (const float*)d_in[4];
    const float* Wfc = (const float*)d_in[5];
    const float* bfc = (const float*)d_in[6];
    const int* edges = (const int*)d_in[7];
    const int* batch = (const int*)d_in[8];

    const int n = in_sizes[8];        // 100000
    const int E = in_sizes[7] / 2;    // 1600000
    const int* esrc = edges;
    const int* edst = edges + E;

    const int NB = (n + 255) >> 8;            // 391 coarse buckets
    const int T = NB * NBLK;
    const int chunk = (E + NBLK - 1) / NBLK;

    char* p = (char*)d_ws;
    auto carve = [&](size_t bytes) {
        void* r = (void*)p;
        p += (bytes + 255) & ~(size_t)255;
        return r;
    };
    int*    bhT       = (int*)carve((size_t)T * 4);
    int*    off       = (int*)carve((size_t)T * 4);
    int*    bsums     = (int*)carve(512);
    int*    ebuf      = (int*)carve((size_t)E * 4);
    int*    meta      = (int*)carve((size_t)n * 4);
    float*  dinv      = (float*)carve((size_t)n * 4);
    int*    ssrc      = (int*)carve(((size_t)E + (size_t)NB * PADB) * 4);
    ushort* xb        = (ushort*)carve((size_t)(n + 1) * CH * 2);  // x, later h1
    ushort* yb        = (ushort*)carve((size_t)(n + 1) * CH * 2);  // y, later z
    ushort* Wt        = (ushort*)carve((size_t)CH * CH * 2);
    float*  q         = (float*)carve((size_t)NG * CH * 4);
    float*  cnt       = (float*)carve((size_t)NG * 4);
    float*  Wc        = (float*)carve((size_t)CH * OC * 4);
    float*  bc        = (float*)carve((size_t)OC * 4);

    int nScanBlocks = (T + 1023) / 1024;
    int npb = (n + POOLB - 1) / POOLB;

    // CSR build (atomic-free global ordering, rows padded x16)
    k_hist<<<NBLK, 256, 0, stream>>>(edst, bhT, E, NB, chunk);
    k_scan1<<<nScanBlocks, 256, 0, stream>>>(bhT, off, bsums, T);
    k_scan2<<<1, 128, 0, stream>>>(bsums, nScanBlocks);
    k_part<<<NBLK, 256, 0, stream>>>(esrc, edst, off, bsums, ebuf, E, NB, chunk);
    k_csr<<<NB, 256, 0, stream>>>(ebuf, off, bsums, meta, dinv, ssrc, n, NB, E);

    // features + weight prep (+ q/cnt zeroing)
    k_cvt<<<(n * CH / 4 + 255) / 256, 256, 0, stream>>>(x, dinv, xb, n, n * CH);
    k_prep<<<(CH * CH + CH * OC + OC + 255) / 256, 256, 0, stream>>>(
        W1, W2, b2, Wfc, bfc, Wt, Wc, bc, q, cnt);
    // y = dinv*(sum Xs + self)   (xb -> yb)
    k_agg<<<(n + 3) / 4, 256, 0, stream>>>(xb, meta, ssrc, dinv, yb, n);
    // h1s = dinv*relu(y*W1 + b1)   (yb -> xb; sentinel row n in xb stays 0)
    k_gemm_mfma<<<(n + 127) / 128, 256, 0, stream>>>(yb, Wt, b1, dinv, xb, n);
    // z = dinv*(sum H1s + self)   (xb -> yb)
    k_agg<<<(n + 3) / 4, 256, 0, stream>>>(xb, meta, ssrc, dinv, yb, n);
    // q = sum-pool(z), cnt via atomics
    k_pool<<<POOLB, 256, 0, stream>>>(yb, batch, q, cnt, n, npb);
    // out = (q/cnt)*Wc + bc
    k_out<<<(NG * OC + 255) / 256, 256, 0, stream>>>(q, cnt, Wc, bc, (float*)d_out);
}